// Round 2
// baseline (1113.174 us; speedup 1.0000x reference)
//
#include <hip/hip_runtime.h>
#include <stdint.h>

typedef unsigned int u32;
typedef unsigned long long u64;

#define N_BOXES 6291456   // 128*128*128*3
#define KCAND 4096
#define TOPK 300
#define CAP 16384         // compact capacity; need >= 4095 + B* bin population (~8.5K for this data)
#define SCORE_TH -3.0f
#define NMS_TH 0.05f

__device__ __forceinline__ u32 sortable(float f) {
    u32 b = __float_as_uint(f);
    return (b & 0x80000000u) ? ~b : (b | 0x80000000u);
}

// ---- Pass 1: 4096-bin histogram of top-12 bits of sortable key ----
__global__ void k_hist(const float* __restrict__ in, u32* __restrict__ hist) {
    __shared__ u32 lh[4096];
    for (int k = threadIdx.x; k < 4096; k += blockDim.x) lh[k] = 0;
    __syncthreads();
    int stride = gridDim.x * blockDim.x;
    for (int i = blockIdx.x * blockDim.x + threadIdx.x; i < N_BOXES; i += stride) {
        float f = in[(size_t)i * 5];
        u32 key = (f > SCORE_TH) ? sortable(f) : 0u;
        atomicAdd(&lh[key >> 20], 1u);
    }
    __syncthreads();
    for (int k = threadIdx.x; k < 4096; k += blockDim.x)
        if (lh[k]) atomicAdd(&hist[k], lh[k]);
}

// ---- Pass 2: find bin B* containing the 4096th largest key ----
__global__ void k_pivot(const u32* __restrict__ hist, u32* __restrict__ cnt) {
    __shared__ u32 part[256];
    int t = threadIdx.x;
    u32 s = 0;
    for (int k = 0; k < 16; ++k) s += hist[t * 16 + k];
    part[t] = s;
    __syncthreads();
    if (t == 0) {
        u32 acc = 0; int chunk = -1;
        for (int c = 255; c >= 0; --c) {
            if (acc + part[c] >= (u32)KCAND) { chunk = c; break; }
            acc += part[c];
        }
        u32 bstar = 0;
        if (chunk >= 0) {
            for (int b = chunk * 16 + 15; b >= chunk * 16; --b) {
                acc += hist[b];
                if (acc >= (u32)KCAND) { bstar = (u32)b; break; }
            }
        }
        cnt[1] = bstar;
    }
}

// ---- Pass 3: compact all candidates with bin >= B* ----
__global__ void k_compact(const float* __restrict__ in, u32* __restrict__ cnt,
                          u32* __restrict__ ckey, u32* __restrict__ cidx) {
    u32 bstar = cnt[1];
    int stride = gridDim.x * blockDim.x;
    for (int i = blockIdx.x * blockDim.x + threadIdx.x; i < N_BOXES; i += stride) {
        float f = in[(size_t)i * 5];
        u32 key = (f > SCORE_TH) ? sortable(f) : 0u;
        if ((key >> 20) >= bstar) {
            u32 pos = atomicAdd(&cnt[0], 1u);
            if (pos < (u32)CAP) { ckey[pos] = key; cidx[pos] = (u32)i; }
        }
    }
}

// ---- Pass 4: exact rank by (key desc, idx asc); grid (CAP/256, CAP/1024) ----
__global__ void k_rank(const u32* __restrict__ ckey, const u32* __restrict__ cidx,
                       const u32* __restrict__ cnt, u32* __restrict__ rank) {
    int M = (int)min(cnt[0], (u32)CAP);
    int e = blockIdx.x * 256 + threadIdx.x;
    bool act = (e < M);
    u32 mykey = 0, myidx = 0;
    if (act) { mykey = ckey[e]; myidx = cidx[e]; }
    int j0 = blockIdx.y * 1024;
    int j1 = min(j0 + 1024, M);
    __shared__ u32 sk[256], si[256];
    u32 r = 0;
    for (int base = j0; base < j1; base += 256) {
        __syncthreads();
        int jj = base + threadIdx.x;
        if (jj < j1) { sk[threadIdx.x] = ckey[jj]; si[threadIdx.x] = cidx[jj]; }
        __syncthreads();
        int lim = min(256, j1 - base);
        if (act) {
            for (int q = 0; q < lim; ++q) {
                u32 kq = sk[q];
                r += (u32)((kq > mykey) || (kq == mykey && si[q] < myidx));
            }
        }
    }
    if (act && r) atomicAdd(&rank[e], r);
}

__global__ void k_scatter(const u32* __restrict__ ckey, const u32* __restrict__ cidx,
                          const u32* __restrict__ cnt, const u32* __restrict__ rank,
                          u32* __restrict__ skey, u32* __restrict__ sidx) {
    int M = (int)min(cnt[0], (u32)CAP);
    int e = blockIdx.x * 256 + threadIdx.x;
    if (e < M) {
        u32 r = rank[e];
        if (r < (u32)KCAND) { skey[r] = ckey[e]; sidx[r] = cidx[e]; }
    }
}

// ---- Pass 5: decode the 4096 selected boxes; build validity bitmask ----
__global__ void k_decode(const float* __restrict__ in, const u32* __restrict__ skey,
                         const u32* __restrict__ sidx, float* __restrict__ cand,
                         u64* __restrict__ keepg) {
#pragma clang fp contract(off)
    int r = blockIdx.x * 256 + threadIdx.x;   // grid 16 x 256 = 4096 exactly
    u32 key = skey[r];
    u32 idx = sidx[r];
    u32 a = idx % 3u;
    u32 rem = idx / 3u;
    u32 w = rem & 127u; rem >>= 7;
    u32 h = rem & 127u;
    u32 z = rem >> 7;
    float anch = (a == 0u) ? 10.0f : ((a == 1u) ? 30.0f : 60.0f);
    const float* p = in + (size_t)idx * 5;
    float s  = p[0];
    float zc = (1.5f + 4.0f * (float)z) + p[1] * anch;
    float yc = (1.5f + 4.0f * (float)h) + p[2] * anch;
    float xc = (1.5f + 4.0f * (float)w) + p[3] * anch;
    float d  = expf(p[4]) * anch;
    float* o = cand + (size_t)r * 5;
    o[0] = s; o[1] = zc; o[2] = yc; o[3] = xc; o[4] = d;
    u64 bal = __ballot(key != 0u);    // valid = score > THRESH (key==0 means filtered)
    if ((threadIdx.x & 63) == 0) keepg[r >> 6] = bal;
}

// ---- Pass 6: 4096x4096 suppression bitmask (bit set iff j>i && iou>=th) ----
__global__ void k_mask(const float* __restrict__ cand, u64* __restrict__ mask) {
#pragma clang fp contract(off)
    int i = blockIdx.y;
    int wv = blockIdx.x * 4 + (threadIdx.x >> 6);
    int j = wv * 64 + (threadIdx.x & 63);
    const float* bi = cand + (size_t)i * 5;
    const float* bj = cand + (size_t)j * 5;
    float zi = bi[1], yi = bi[2], xi = bi[3], di = bi[4];
    float zj = bj[1], yj = bj[2], xj = bj[3], dj = bj[4];
    float ri = di * 0.5f, rj = dj * 0.5f;
    float ov0 = fmaxf(0.0f, fminf(zi + ri, zj + rj) - fmaxf(zi - ri, zj - rj));
    float ov1 = fmaxf(0.0f, fminf(yi + ri, yj + rj) - fmaxf(yi - ri, yj - rj));
    float ov2 = fmaxf(0.0f, fminf(xi + ri, xj + rj) - fmaxf(xi - ri, xj - rj));
    float inter = (ov0 * ov1) * ov2;
    float vi = (di * di) * di;
    float vj = (dj * dj) * dj;
    float iou = inter / ((vi + vj) - inter);
    bool bit = (j > i) && (iou >= NMS_TH);
    u64 bal = __ballot(bit);
    if ((threadIdx.x & 63) == 0) mask[(size_t)i * 64 + wv] = bal;
}

// ---- Pass 7: sequential greedy NMS over the bitmask (1 block, 64 threads) ----
__global__ void k_nms(const u64* __restrict__ mask, u64* __restrict__ keepg) {
    __shared__ u64 keep[64];
    __shared__ u64 tile[64];
    int t = threadIdx.x;
    keep[t] = keepg[t];
    __syncthreads();
    for (int c = 0; c < 64; ++c) {
        tile[t] = mask[(size_t)(c * 64 + t) * 64 + c];
        __syncthreads();
        if (t == 0) {
            u64 kw = keep[c];
            for (int b = 0; b < 64; ++b)
                if ((kw >> b) & 1ull) kw &= ~tile[b];
            keep[c] = kw;
        }
        __syncthreads();
        u64 kw = keep[c];
        for (int b = 0; b < 64; ++b) {
            if ((kw >> b) & 1ull) {
                u64 row = mask[(size_t)(c * 64 + b) * 64 + t];
                keep[t] &= ~row;    // rows only have bits j>i, so earlier words are 0
            }
        }
        __syncthreads();
    }
    keepg[t] = keep[t];
}

// ---- Pass 8: final top-300 = kept positions asc, then non-kept asc ----
__global__ void k_final(const float* __restrict__ cand, const u64* __restrict__ keepg,
                        float* __restrict__ outp) {
    __shared__ u64 kw[64];
    __shared__ u32 wp[65];
    int t = threadIdx.x;   // 256
    if (t < 64) kw[t] = keepg[t];
    __syncthreads();
    if (t == 0) {
        u32 acc = 0;
        for (int wv = 0; wv < 64; ++wv) { wp[wv] = acc; acc += (u32)__popcll(kw[wv]); }
        wp[64] = acc;
    }
    __syncthreads();
    u32 nk = wp[64];
    for (int r = t; r < KCAND; r += 256) {
        u64 word = kw[r >> 6];
        int b = r & 63;
        bool kept = (word >> b) & 1ull;
        u64 lowmask = b ? (~0ull >> (64 - b)) : 0ull;
        u32 before = wp[r >> 6] + (u32)__popcll(word & lowmask);
        u32 slot = kept ? before : (nk + (u32)r - before);
        if (slot < (u32)TOPK) {
            const float* src = cand + (size_t)r * 5;
            float* dst = outp + (size_t)slot * 5;
            dst[0] = src[0]; dst[1] = src[1]; dst[2] = src[2];
            dst[3] = src[3]; dst[4] = src[4];
        }
    }
}

extern "C" void kernel_launch(void* const* d_in, const int* in_sizes, int n_in,
                              void* d_out, int out_size, void* d_ws, size_t ws_size,
                              hipStream_t stream) {
    const float* in = (const float*)d_in[0];
    float* outp = (float*)d_out;
    char* ws = (char*)d_ws;

    // workspace layout (bytes), CAP = 16384
    u32* hist = (u32*)(ws + 0);            // 16384
    u32* cnt  = (u32*)(ws + 16384);        // 64
    u32* rank = (u32*)(ws + 16448);        // 65536
    u32* ckey = (u32*)(ws + 81984);        // 65536
    u32* cidx = (u32*)(ws + 147520);       // 65536
    u32* skey = (u32*)(ws + 213056);       // 16384
    u32* sidx = (u32*)(ws + 229440);       // 16384
    float* cand = (float*)(ws + 245824);   // 81920
    u64* keepg  = (u64*)(ws + 327744);     // 512
    u64* mask   = (u64*)(ws + 328256);     // 2097152   (total ~2.43 MB)

    hipMemsetAsync(hist, 0, 16384 + 64, stream);   // hist + cnt
    hipMemsetAsync(rank, 0, 65536, stream);

    k_hist   <<<2048, 256, 0, stream>>>(in, hist);
    k_pivot  <<<1, 256, 0, stream>>>(hist, cnt);
    k_compact<<<2048, 256, 0, stream>>>(in, cnt, ckey, cidx);
    k_rank   <<<dim3(64, 16), 256, 0, stream>>>(ckey, cidx, cnt, rank);
    k_scatter<<<64, 256, 0, stream>>>(ckey, cidx, cnt, rank, skey, sidx);
    k_decode <<<16, 256, 0, stream>>>(in, skey, sidx, cand, keepg);
    k_mask   <<<dim3(16, 4096), 256, 0, stream>>>(cand, mask);
    k_nms    <<<1, 64, 0, stream>>>(mask, keepg);
    k_final  <<<1, 256, 0, stream>>>(cand, keepg, outp);
}

// Round 3
// 513.642 us; speedup vs baseline: 2.1672x; 2.1672x over previous
//
#include <hip/hip_runtime.h>
#include <stdint.h>

typedef unsigned int u32;
typedef unsigned long long u64;

#define N_BOXES 6291456   // 128*128*128*3
#define KCAND 4096
#define TOPK 300
#define CAP 16384         // compact capacity; need >= 4095 + B* bin population (~8.5K for this data)
#define SCORE_TH -3.0f
#define NMS_TH 0.05f

__device__ __forceinline__ u32 sortable(float f) {
    u32 b = __float_as_uint(f);
    return (b & 0x80000000u) ? ~b : (b | 0x80000000u);
}

// ---- Pass 1: 4096-bin histogram of top-12 bits of sortable key ----
__global__ void k_hist(const float* __restrict__ in, u32* __restrict__ hist) {
    __shared__ u32 lh[4096];
    for (int k = threadIdx.x; k < 4096; k += blockDim.x) lh[k] = 0;
    __syncthreads();
    int stride = gridDim.x * blockDim.x;
    for (int i = blockIdx.x * blockDim.x + threadIdx.x; i < N_BOXES; i += stride) {
        float f = in[(size_t)i * 5];
        u32 key = (f > SCORE_TH) ? sortable(f) : 0u;
        atomicAdd(&lh[key >> 20], 1u);
    }
    __syncthreads();
    for (int k = threadIdx.x; k < 4096; k += blockDim.x)
        if (lh[k]) atomicAdd(&hist[k], lh[k]);
}

// ---- Pass 2: find bin B* containing the 4096th largest key ----
__global__ void k_pivot(const u32* __restrict__ hist, u32* __restrict__ cnt) {
    __shared__ u32 part[256];
    int t = threadIdx.x;
    u32 s = 0;
    for (int k = 0; k < 16; ++k) s += hist[t * 16 + k];
    part[t] = s;
    __syncthreads();
    if (t == 0) {
        u32 acc = 0; int chunk = -1;
        for (int c = 255; c >= 0; --c) {
            if (acc + part[c] >= (u32)KCAND) { chunk = c; break; }
            acc += part[c];
        }
        u32 bstar = 0;
        if (chunk >= 0) {
            for (int b = chunk * 16 + 15; b >= chunk * 16; --b) {
                acc += hist[b];
                if (acc >= (u32)KCAND) { bstar = (u32)b; break; }
            }
        }
        cnt[1] = bstar;
    }
}

// ---- Pass 3: compact all candidates with bin >= B* ----
__global__ void k_compact(const float* __restrict__ in, u32* __restrict__ cnt,
                          u32* __restrict__ ckey, u32* __restrict__ cidx) {
    u32 bstar = cnt[1];
    int stride = gridDim.x * blockDim.x;
    for (int i = blockIdx.x * blockDim.x + threadIdx.x; i < N_BOXES; i += stride) {
        float f = in[(size_t)i * 5];
        u32 key = (f > SCORE_TH) ? sortable(f) : 0u;
        if ((key >> 20) >= bstar) {
            u32 pos = atomicAdd(&cnt[0], 1u);
            if (pos < (u32)CAP) { ckey[pos] = key; cidx[pos] = (u32)i; }
        }
    }
}

// ---- Pass 4: exact rank by (key desc, idx asc); grid (CAP/256, CAP/1024) ----
__global__ void k_rank(const u32* __restrict__ ckey, const u32* __restrict__ cidx,
                       const u32* __restrict__ cnt, u32* __restrict__ rank) {
    int M = (int)min(cnt[0], (u32)CAP);
    int e = blockIdx.x * 256 + threadIdx.x;
    bool act = (e < M);
    u32 mykey = 0, myidx = 0;
    if (act) { mykey = ckey[e]; myidx = cidx[e]; }
    int j0 = blockIdx.y * 1024;
    int j1 = min(j0 + 1024, M);
    __shared__ u32 sk[256], si[256];
    u32 r = 0;
    for (int base = j0; base < j1; base += 256) {
        __syncthreads();
        int jj = base + threadIdx.x;
        if (jj < j1) { sk[threadIdx.x] = ckey[jj]; si[threadIdx.x] = cidx[jj]; }
        __syncthreads();
        int lim = min(256, j1 - base);
        if (act) {
            for (int q = 0; q < lim; ++q) {
                u32 kq = sk[q];
                r += (u32)((kq > mykey) || (kq == mykey && si[q] < myidx));
            }
        }
    }
    if (act && r) atomicAdd(&rank[e], r);
}

__global__ void k_scatter(const u32* __restrict__ ckey, const u32* __restrict__ cidx,
                          const u32* __restrict__ cnt, const u32* __restrict__ rank,
                          u32* __restrict__ skey, u32* __restrict__ sidx) {
    int M = (int)min(cnt[0], (u32)CAP);
    int e = blockIdx.x * 256 + threadIdx.x;
    if (e < M) {
        u32 r = rank[e];
        if (r < (u32)KCAND) { skey[r] = ckey[e]; sidx[r] = cidx[e]; }
    }
}

// ---- Pass 5: decode the 4096 selected boxes; build validity bitmask ----
__global__ void k_decode(const float* __restrict__ in, const u32* __restrict__ skey,
                         const u32* __restrict__ sidx, float* __restrict__ cand,
                         u64* __restrict__ keepg) {
#pragma clang fp contract(off)
    int r = blockIdx.x * 256 + threadIdx.x;   // grid 16 x 256 = 4096 exactly
    u32 key = skey[r];
    u32 idx = sidx[r];
    u32 a = idx % 3u;
    u32 rem = idx / 3u;
    u32 w = rem & 127u; rem >>= 7;
    u32 h = rem & 127u;
    u32 z = rem >> 7;
    float anch = (a == 0u) ? 10.0f : ((a == 1u) ? 30.0f : 60.0f);
    const float* p = in + (size_t)idx * 5;
    float s  = p[0];
    float zc = (1.5f + 4.0f * (float)z) + p[1] * anch;
    float yc = (1.5f + 4.0f * (float)h) + p[2] * anch;
    float xc = (1.5f + 4.0f * (float)w) + p[3] * anch;
    float d  = expf(p[4]) * anch;
    float* o = cand + (size_t)r * 5;
    o[0] = s; o[1] = zc; o[2] = yc; o[3] = xc; o[4] = d;
    u64 bal = __ballot(key != 0u);    // valid = score > THRESH (key==0 means filtered)
    if ((threadIdx.x & 63) == 0) keepg[r >> 6] = bal;
}

// ---- Pass 6: 4096x4096 suppression bitmask (bit set iff j>i && iou>=th) ----
__global__ void k_mask(const float* __restrict__ cand, u64* __restrict__ mask) {
#pragma clang fp contract(off)
    int i = blockIdx.y;
    int wv = blockIdx.x * 4 + (threadIdx.x >> 6);
    int j = wv * 64 + (threadIdx.x & 63);
    const float* bi = cand + (size_t)i * 5;
    const float* bj = cand + (size_t)j * 5;
    float zi = bi[1], yi = bi[2], xi = bi[3], di = bi[4];
    float zj = bj[1], yj = bj[2], xj = bj[3], dj = bj[4];
    float ri = di * 0.5f, rj = dj * 0.5f;
    float ov0 = fmaxf(0.0f, fminf(zi + ri, zj + rj) - fmaxf(zi - ri, zj - rj));
    float ov1 = fmaxf(0.0f, fminf(yi + ri, yj + rj) - fmaxf(yi - ri, yj - rj));
    float ov2 = fmaxf(0.0f, fminf(xi + ri, xj + rj) - fmaxf(xi - ri, xj - rj));
    float inter = (ov0 * ov1) * ov2;
    float vi = (di * di) * di;
    float vj = (dj * dj) * dj;
    float iou = inter / ((vi + vj) - inter);
    bool bit = (j > i) && (iou >= NMS_TH);
    u64 bal = __ballot(bit);
    if ((threadIdx.x & 63) == 0) mask[(size_t)i * 64 + wv] = bal;
}

// ---- Pass 7: greedy NMS, chunk tiles staged in LDS, double-buffered ----
// Exact same semantics as the sequential reference loop.
__global__ __launch_bounds__(1024) void k_nms(const u64* __restrict__ mask,
                                              u64* __restrict__ keepg) {
    __shared__ u64 keep[64];
    __shared__ u64 tileT[2][64][65];   // [buf][word][row], +1 pad
    int t = threadIdx.x;
    int lane = t & 63;
    int wave = t >> 6;                 // 0..15
    int row = t >> 4;                  // 0..63  (16 threads per row)
    int w0  = (t & 15) * 4;            // word group start
    if (t < 64) keep[t] = keepg[t];
    // prefetch chunk 0 into buf 0
    {
        const u64* src = mask + ((size_t)row * 64 + w0);
        u64 a0 = src[0], a1 = src[1], a2 = src[2], a3 = src[3];
        tileT[0][w0+0][row] = a0;
        tileT[0][w0+1][row] = a1;
        tileT[0][w0+2][row] = a2;
        tileT[0][w0+3][row] = a3;
    }
    __syncthreads();
    int cur = 0;
    for (int c = 0; c < 64; ++c) {
        // issue next chunk's global loads (latency hides under resolve/apply)
        u64 a0 = 0, a1 = 0, a2 = 0, a3 = 0;
        if (c + 1 < 64) {
            const u64* src = mask + ((size_t)((c + 1) * 64 + row) * 64 + w0);
            a0 = src[0]; a1 = src[1]; a2 = src[2]; a3 = src[3];
        }
        // resolve intra-chunk greedy on wave 0 (kw is wave-uniform)
        if (wave == 0) {
            u64 diag = tileT[cur][c][lane];   // row 'lane', word c
            u64 kw = keep[c];
            #pragma unroll
            for (int b = 0; b < 64; ++b) {
                u64 rb = __shfl(diag, b, 64);
                if ((kw >> b) & 1ull) kw &= ~rb;   // rb only has bits > b
            }
            if (lane == 0) keep[c] = kw;
        }
        __syncthreads();
        u64 kw = keep[c];
        // apply suppression from kept rows of chunk c to words t > c
        for (int w = c + 1 + wave; w < 64; w += 16) {
            u64 v = ((kw >> lane) & 1ull) ? tileT[cur][w][lane] : 0ull;
            #pragma unroll
            for (int s = 32; s; s >>= 1) v |= __shfl_xor(v, s, 64);
            if (lane == 0) keep[w] &= ~v;
        }
        // store prefetched tile into the other buffer
        if (c + 1 < 64) {
            tileT[cur ^ 1][w0+0][row] = a0;
            tileT[cur ^ 1][w0+1][row] = a1;
            tileT[cur ^ 1][w0+2][row] = a2;
            tileT[cur ^ 1][w0+3][row] = a3;
        }
        __syncthreads();
        cur ^= 1;
    }
    if (t < 64) keepg[t] = keep[t];
}

// ---- Pass 8: final top-300 = kept positions asc, then non-kept asc ----
__global__ void k_final(const float* __restrict__ cand, const u64* __restrict__ keepg,
                        float* __restrict__ outp) {
    __shared__ u64 kw[64];
    __shared__ u32 wp[65];
    int t = threadIdx.x;   // 256
    if (t < 64) kw[t] = keepg[t];
    __syncthreads();
    if (t == 0) {
        u32 acc = 0;
        for (int wv = 0; wv < 64; ++wv) { wp[wv] = acc; acc += (u32)__popcll(kw[wv]); }
        wp[64] = acc;
    }
    __syncthreads();
    u32 nk = wp[64];
    for (int r = t; r < KCAND; r += 256) {
        u64 word = kw[r >> 6];
        int b = r & 63;
        bool kept = (word >> b) & 1ull;
        u64 lowmask = b ? (~0ull >> (64 - b)) : 0ull;
        u32 before = wp[r >> 6] + (u32)__popcll(word & lowmask);
        u32 slot = kept ? before : (nk + (u32)r - before);
        if (slot < (u32)TOPK) {
            const float* src = cand + (size_t)r * 5;
            float* dst = outp + (size_t)slot * 5;
            dst[0] = src[0]; dst[1] = src[1]; dst[2] = src[2];
            dst[3] = src[3]; dst[4] = src[4];
        }
    }
}

extern "C" void kernel_launch(void* const* d_in, const int* in_sizes, int n_in,
                              void* d_out, int out_size, void* d_ws, size_t ws_size,
                              hipStream_t stream) {
    const float* in = (const float*)d_in[0];
    float* outp = (float*)d_out;
    char* ws = (char*)d_ws;

    // workspace layout (bytes), CAP = 16384
    u32* hist = (u32*)(ws + 0);            // 16384
    u32* cnt  = (u32*)(ws + 16384);        // 64
    u32* rank = (u32*)(ws + 16448);        // 65536
    u32* ckey = (u32*)(ws + 81984);        // 65536
    u32* cidx = (u32*)(ws + 147520);       // 65536
    u32* skey = (u32*)(ws + 213056);       // 16384
    u32* sidx = (u32*)(ws + 229440);       // 16384
    float* cand = (float*)(ws + 245824);   // 81920
    u64* keepg  = (u64*)(ws + 327744);     // 512
    u64* mask   = (u64*)(ws + 328256);     // 2097152   (total ~2.43 MB)

    hipMemsetAsync(hist, 0, 16384 + 64, stream);   // hist + cnt
    hipMemsetAsync(rank, 0, 65536, stream);

    k_hist   <<<2048, 256, 0, stream>>>(in, hist);
    k_pivot  <<<1, 256, 0, stream>>>(hist, cnt);
    k_compact<<<2048, 256, 0, stream>>>(in, cnt, ckey, cidx);
    k_rank   <<<dim3(64, 16), 256, 0, stream>>>(ckey, cidx, cnt, rank);
    k_scatter<<<64, 256, 0, stream>>>(ckey, cidx, cnt, rank, skey, sidx);
    k_decode <<<16, 256, 0, stream>>>(in, skey, sidx, cand, keepg);
    k_mask   <<<dim3(16, 4096), 256, 0, stream>>>(cand, mask);
    k_nms    <<<1, 1024, 0, stream>>>(mask, keepg);
    k_final  <<<1, 256, 0, stream>>>(cand, keepg, outp);
}

// Round 5
// 408.142 us; speedup vs baseline: 2.7274x; 1.2585x over previous
//
#include <hip/hip_runtime.h>
#include <stdint.h>

typedef unsigned int u32;
typedef unsigned long long u64;

#define N_BOXES 6291456   // 128*128*128*3
#define KCAND 4096
#define TOPK 300
#define CAP 16384         // compact capacity; need >= 4095 + B* bin population (~8.5K for this data)
#define SCORE_TH -3.0f
#define NMS_TH 0.05f

__device__ __forceinline__ u32 sortable(float f) {
    u32 b = __float_as_uint(f);
    return (b & 0x80000000u) ? ~b : (b | 0x80000000u);
}

// ---- Pass 1: 4096-bin histogram of top-12 bits of sortable key ----
__global__ void k_hist(const float* __restrict__ in, u32* __restrict__ hist) {
    __shared__ u32 lh[4096];
    for (int k = threadIdx.x; k < 4096; k += blockDim.x) lh[k] = 0;
    __syncthreads();
    int stride = gridDim.x * blockDim.x;
    for (int i = blockIdx.x * blockDim.x + threadIdx.x; i < N_BOXES; i += stride) {
        float f = in[(size_t)i * 5];
        u32 key = (f > SCORE_TH) ? sortable(f) : 0u;
        atomicAdd(&lh[key >> 20], 1u);
    }
    __syncthreads();
    for (int k = threadIdx.x; k < 4096; k += blockDim.x)
        if (lh[k]) atomicAdd(&hist[k], lh[k]);
}

// ---- Pass 2: find bin B* containing the 4096th largest key ----
__global__ void k_pivot(const u32* __restrict__ hist, u32* __restrict__ cnt) {
    __shared__ u32 part[256];
    int t = threadIdx.x;
    u32 s = 0;
    for (int k = 0; k < 16; ++k) s += hist[t * 16 + k];
    part[t] = s;
    __syncthreads();
    if (t == 0) {
        u32 acc = 0; int chunk = -1;
        for (int c = 255; c >= 0; --c) {
            if (acc + part[c] >= (u32)KCAND) { chunk = c; break; }
            acc += part[c];
        }
        u32 bstar = 0;
        if (chunk >= 0) {
            for (int b = chunk * 16 + 15; b >= chunk * 16; --b) {
                acc += hist[b];
                if (acc >= (u32)KCAND) { bstar = (u32)b; break; }
            }
        }
        cnt[1] = bstar;
    }
}

// ---- Pass 3: compact all candidates with bin >= B* ----
__global__ void k_compact(const float* __restrict__ in, u32* __restrict__ cnt,
                          u32* __restrict__ ckey, u32* __restrict__ cidx) {
    u32 bstar = cnt[1];
    int stride = gridDim.x * blockDim.x;
    for (int i = blockIdx.x * blockDim.x + threadIdx.x; i < N_BOXES; i += stride) {
        float f = in[(size_t)i * 5];
        u32 key = (f > SCORE_TH) ? sortable(f) : 0u;
        if ((key >> 20) >= bstar) {
            u32 pos = atomicAdd(&cnt[0], 1u);
            if (pos < (u32)CAP) { ckey[pos] = key; cidx[pos] = (u32)i; }
        }
    }
}

// ---- Pass 4: exact rank by (key desc, idx asc); grid (CAP/256, CAP/1024) ----
__global__ void k_rank(const u32* __restrict__ ckey, const u32* __restrict__ cidx,
                       const u32* __restrict__ cnt, u32* __restrict__ rank) {
    int M = (int)min(cnt[0], (u32)CAP);
    int e = blockIdx.x * 256 + threadIdx.x;
    bool act = (e < M);
    u32 mykey = 0, myidx = 0;
    if (act) { mykey = ckey[e]; myidx = cidx[e]; }
    int j0 = blockIdx.y * 1024;
    int j1 = min(j0 + 1024, M);
    __shared__ u32 sk[256], si[256];
    u32 r = 0;
    for (int base = j0; base < j1; base += 256) {
        __syncthreads();
        int jj = base + threadIdx.x;
        if (jj < j1) { sk[threadIdx.x] = ckey[jj]; si[threadIdx.x] = cidx[jj]; }
        __syncthreads();
        int lim = min(256, j1 - base);
        if (act) {
            for (int q = 0; q < lim; ++q) {
                u32 kq = sk[q];
                r += (u32)((kq > mykey) || (kq == mykey && si[q] < myidx));
            }
        }
    }
    if (act && r) atomicAdd(&rank[e], r);
}

__global__ void k_scatter(const u32* __restrict__ ckey, const u32* __restrict__ cidx,
                          const u32* __restrict__ cnt, const u32* __restrict__ rank,
                          u32* __restrict__ skey, u32* __restrict__ sidx) {
    int M = (int)min(cnt[0], (u32)CAP);
    int e = blockIdx.x * 256 + threadIdx.x;
    if (e < M) {
        u32 r = rank[e];
        if (r < (u32)KCAND) { skey[r] = ckey[e]; sidx[r] = cidx[e]; }
    }
}

// ---- Pass 5: decode the 4096 selected boxes; build validity bitmask ----
__global__ void k_decode(const float* __restrict__ in, const u32* __restrict__ skey,
                         const u32* __restrict__ sidx, float* __restrict__ cand,
                         u64* __restrict__ keepg) {
#pragma clang fp contract(off)
    int r = blockIdx.x * 256 + threadIdx.x;   // grid 16 x 256 = 4096 exactly
    u32 key = skey[r];
    u32 idx = sidx[r];
    u32 a = idx % 3u;
    u32 rem = idx / 3u;
    u32 w = rem & 127u; rem >>= 7;
    u32 h = rem & 127u;
    u32 z = rem >> 7;
    float anch = (a == 0u) ? 10.0f : ((a == 1u) ? 30.0f : 60.0f);
    const float* p = in + (size_t)idx * 5;
    float s  = p[0];
    float zc = (1.5f + 4.0f * (float)z) + p[1] * anch;
    float yc = (1.5f + 4.0f * (float)h) + p[2] * anch;
    float xc = (1.5f + 4.0f * (float)w) + p[3] * anch;
    float d  = expf(p[4]) * anch;
    float* o = cand + (size_t)r * 5;
    o[0] = s; o[1] = zc; o[2] = yc; o[3] = xc; o[4] = d;
    u64 bal = __ballot(key != 0u);    // valid = score > THRESH (key==0 means filtered)
    if ((threadIdx.x & 63) == 0) keepg[r >> 6] = bal;
}

// ---- Pass 6: 4096x4096 suppression bitmask (bit set iff j>i && iou>=th) ----
__global__ void k_mask(const float* __restrict__ cand, u64* __restrict__ mask) {
#pragma clang fp contract(off)
    int i = blockIdx.y;
    int wv = blockIdx.x * 4 + (threadIdx.x >> 6);
    int j = wv * 64 + (threadIdx.x & 63);
    const float* bi = cand + (size_t)i * 5;
    const float* bj = cand + (size_t)j * 5;
    float zi = bi[1], yi = bi[2], xi = bi[3], di = bi[4];
    float zj = bj[1], yj = bj[2], xj = bj[3], dj = bj[4];
    float ri = di * 0.5f, rj = dj * 0.5f;
    float ov0 = fmaxf(0.0f, fminf(zi + ri, zj + rj) - fmaxf(zi - ri, zj - rj));
    float ov1 = fmaxf(0.0f, fminf(yi + ri, yj + rj) - fmaxf(yi - ri, yj - rj));
    float ov2 = fmaxf(0.0f, fminf(xi + ri, xj + rj) - fmaxf(xi - ri, xj - rj));
    float inter = (ov0 * ov1) * ov2;
    float vi = (di * di) * di;
    float vj = (dj * dj) * dj;
    float iou = inter / ((vi + vj) - inter);
    bool bit = (j > i) && (iou >= NMS_TH);
    u64 bal = __ballot(bit);
    if ((threadIdx.x & 63) == 0) mask[(size_t)i * 64 + wv] = bal;
}

// ---- Pass 7: greedy NMS — single wave, scalar resolve + vector apply ----
// lane l holds keep word l. LDS double-buffers one 64x64-word chunk tile,
// streamed in with global_load_lds (width 16). No barriers.
// NOTE: word c needs no special fixup: rows carry only bits j>i, so the
// one-shot OR over kept rows reproduces the greedy result exactly.
__global__ __launch_bounds__(64) void k_nms(const u64* __restrict__ mask,
                                            u64* __restrict__ keepg) {
    __shared__ u64 tile[2][4096];   // 2 x 32 KB, linear [row][word]
    int lane = threadIdx.x;
    u64 K = keepg[lane];

    // prologue: stage chunk 0 into tile[0]
    {
        const char* src = (const char*)mask;
        char* dst = (char*)&tile[0][0];
#pragma unroll
        for (int i = 0; i < 32; ++i)
            __builtin_amdgcn_global_load_lds(
                (const __attribute__((address_space(1))) u32*)(src + i * 1024 + lane * 16),
                (__attribute__((address_space(3))) u32*)(dst + i * 1024), 16, 0, 0);
    }

    for (int c = 0; c < 64; ++c) {
        asm volatile("s_waitcnt vmcnt(0)" ::: "memory");
        __builtin_amdgcn_sched_barrier(0);
        const u64* tl = &tile[c & 1][0];
        // issue next chunk's loads (hide under compute)
        if (c + 1 < 64) {
            const char* src = (const char*)(mask + (size_t)(c + 1) * 4096);
            char* dst = (char*)&tile[(c + 1) & 1][0];
#pragma unroll
            for (int i = 0; i < 32; ++i)
                __builtin_amdgcn_global_load_lds(
                    (const __attribute__((address_space(1))) u32*)(src + i * 1024 + lane * 16),
                    (__attribute__((address_space(3))) u32*)(dst + i * 1024), 16, 0, 0);
        }
        // diag: lane b holds row b's word c (intra-chunk suppression bits)
        u64 diag = tl[lane * 64 + c];
        u32 dlo = (u32)diag, dhi = (u32)(diag >> 32);
        // kw = keep word c (wave-uniform)
        u32 kwlo = (u32)__builtin_amdgcn_readlane((int)(u32)K, c);
        u32 kwhi = (u32)__builtin_amdgcn_readlane((int)(u32)(K >> 32), c);
        u64 remaining = ((u64)kwhi << 32) | kwlo;
        // resolve: scalar greedy over surviving bits
        u64 kept = 0;
        while (remaining) {
            int b = __builtin_ctzll(remaining);
            kept |= 1ull << b;
            u32 rlo = (u32)__builtin_amdgcn_readlane((int)dlo, b);
            u32 rhi = (u32)__builtin_amdgcn_readlane((int)dhi, b);
            u64 rb = ((u64)rhi << 32) | rlo;   // bits > b only
            remaining &= ~(rb | (1ull << b));
        }
        // apply: sup_l = OR over kept b of tile[b][l]; rows carry only j>i bits,
        // so sup_l == 0 for l < c automatically, and word c resolves to 'kept'.
        u64 s0 = 0, s1 = 0, s2 = 0, s3 = 0;
#pragma unroll
        for (int b = 0; b < 64; b += 4) {
            u64 m0 = ((kept >> (b + 0)) & 1ull) ? ~0ull : 0ull;
            u64 m1 = ((kept >> (b + 1)) & 1ull) ? ~0ull : 0ull;
            u64 m2 = ((kept >> (b + 2)) & 1ull) ? ~0ull : 0ull;
            u64 m3 = ((kept >> (b + 3)) & 1ull) ? ~0ull : 0ull;
            s0 |= tl[(b + 0) * 64 + lane] & m0;
            s1 |= tl[(b + 1) * 64 + lane] & m1;
            s2 |= tl[(b + 2) * 64 + lane] & m2;
            s3 |= tl[(b + 3) * 64 + lane] & m3;
        }
        K &= ~((s0 | s1) | (s2 | s3));
    }
    keepg[lane] = K;
}

// ---- Pass 8: final top-300 = kept positions asc, then non-kept asc ----
__global__ void k_final(const float* __restrict__ cand, const u64* __restrict__ keepg,
                        float* __restrict__ outp) {
    __shared__ u64 kw[64];
    __shared__ u32 wp[65];
    int t = threadIdx.x;   // 256
    if (t < 64) kw[t] = keepg[t];
    __syncthreads();
    if (t == 0) {
        u32 acc = 0;
        for (int wv = 0; wv < 64; ++wv) { wp[wv] = acc; acc += (u32)__popcll(kw[wv]); }
        wp[64] = acc;
    }
    __syncthreads();
    u32 nk = wp[64];
    for (int r = t; r < KCAND; r += 256) {
        u64 word = kw[r >> 6];
        int b = r & 63;
        bool kept = (word >> b) & 1ull;
        u64 lowmask = b ? (~0ull >> (64 - b)) : 0ull;
        u32 before = wp[r >> 6] + (u32)__popcll(word & lowmask);
        u32 slot = kept ? before : (nk + (u32)r - before);
        if (slot < (u32)TOPK) {
            const float* src = cand + (size_t)r * 5;
            float* dst = outp + (size_t)slot * 5;
            dst[0] = src[0]; dst[1] = src[1]; dst[2] = src[2];
            dst[3] = src[3]; dst[4] = src[4];
        }
    }
}

extern "C" void kernel_launch(void* const* d_in, const int* in_sizes, int n_in,
                              void* d_out, int out_size, void* d_ws, size_t ws_size,
                              hipStream_t stream) {
    const float* in = (const float*)d_in[0];
    float* outp = (float*)d_out;
    char* ws = (char*)d_ws;

    // workspace layout (bytes), CAP = 16384
    u32* hist = (u32*)(ws + 0);            // 16384
    u32* cnt  = (u32*)(ws + 16384);        // 64
    u32* rank = (u32*)(ws + 16448);        // 65536
    u32* ckey = (u32*)(ws + 81984);        // 65536
    u32* cidx = (u32*)(ws + 147520);       // 65536
    u32* skey = (u32*)(ws + 213056);       // 16384
    u32* sidx = (u32*)(ws + 229440);       // 16384
    float* cand = (float*)(ws + 245824);   // 81920
    u64* keepg  = (u64*)(ws + 327744);     // 512
    u64* mask   = (u64*)(ws + 328256);     // 2097152   (total ~2.43 MB)

    hipMemsetAsync(hist, 0, 16384 + 64, stream);   // hist + cnt
    hipMemsetAsync(rank, 0, 65536, stream);

    k_hist   <<<2048, 256, 0, stream>>>(in, hist);
    k_pivot  <<<1, 256, 0, stream>>>(hist, cnt);
    k_compact<<<2048, 256, 0, stream>>>(in, cnt, ckey, cidx);
    k_rank   <<<dim3(64, 16), 256, 0, stream>>>(ckey, cidx, cnt, rank);
    k_scatter<<<64, 256, 0, stream>>>(ckey, cidx, cnt, rank, skey, sidx);
    k_decode <<<16, 256, 0, stream>>>(in, skey, sidx, cand, keepg);
    k_mask   <<<dim3(16, 4096), 256, 0, stream>>>(cand, mask);
    k_nms    <<<1, 64, 0, stream>>>(mask, keepg);
    k_final  <<<1, 256, 0, stream>>>(cand, keepg, outp);
}

// Round 6
// 404.492 us; speedup vs baseline: 2.7520x; 1.0090x over previous
//
#include <hip/hip_runtime.h>
#include <stdint.h>

typedef unsigned int u32;
typedef unsigned long long u64;

#define N_BOXES 6291456   // 128*128*128*3
#define KCAND 4096
#define TOPK 300
#define CAP 16384         // compact capacity; need >= 4095 + B* bin population (~8.5K for this data)
#define SCORE_TH -3.0f
#define NMS_TH 0.05f

#define GLD_LDS16(srcp, dstp) \
    __builtin_amdgcn_global_load_lds( \
        (const __attribute__((address_space(1))) u32*)(srcp), \
        (__attribute__((address_space(3))) u32*)(dstp), 16, 0, 0)

__device__ __forceinline__ u32 sortable(float f) {
    u32 b = __float_as_uint(f);
    return (b & 0x80000000u) ? ~b : (b | 0x80000000u);
}

// ---- Pass 1: 4096-bin histogram of top-12 bits of sortable key ----
__global__ void k_hist(const float* __restrict__ in, u32* __restrict__ hist) {
    __shared__ u32 lh[4096];
    for (int k = threadIdx.x; k < 4096; k += blockDim.x) lh[k] = 0;
    __syncthreads();
    int stride = gridDim.x * blockDim.x;
    for (int i = blockIdx.x * blockDim.x + threadIdx.x; i < N_BOXES; i += stride) {
        float f = in[(size_t)i * 5];
        u32 key = (f > SCORE_TH) ? sortable(f) : 0u;
        atomicAdd(&lh[key >> 20], 1u);
    }
    __syncthreads();
    for (int k = threadIdx.x; k < 4096; k += blockDim.x)
        if (lh[k]) atomicAdd(&hist[k], lh[k]);
}

// ---- Pass 2: find bin B* containing the 4096th largest key ----
__global__ void k_pivot(const u32* __restrict__ hist, u32* __restrict__ cnt) {
    __shared__ u32 part[256];
    int t = threadIdx.x;
    u32 s = 0;
    for (int k = 0; k < 16; ++k) s += hist[t * 16 + k];
    part[t] = s;
    __syncthreads();
    if (t == 0) {
        u32 acc = 0; int chunk = -1;
        for (int c = 255; c >= 0; --c) {
            if (acc + part[c] >= (u32)KCAND) { chunk = c; break; }
            acc += part[c];
        }
        u32 bstar = 0;
        if (chunk >= 0) {
            for (int b = chunk * 16 + 15; b >= chunk * 16; --b) {
                acc += hist[b];
                if (acc >= (u32)KCAND) { bstar = (u32)b; break; }
            }
        }
        cnt[1] = bstar;
    }
}

// ---- Pass 3: compact all candidates with bin >= B* ----
__global__ void k_compact(const float* __restrict__ in, u32* __restrict__ cnt,
                          u32* __restrict__ ckey, u32* __restrict__ cidx) {
    u32 bstar = cnt[1];
    int stride = gridDim.x * blockDim.x;
    for (int i = blockIdx.x * blockDim.x + threadIdx.x; i < N_BOXES; i += stride) {
        float f = in[(size_t)i * 5];
        u32 key = (f > SCORE_TH) ? sortable(f) : 0u;
        if ((key >> 20) >= bstar) {
            u32 pos = atomicAdd(&cnt[0], 1u);
            if (pos < (u32)CAP) { ckey[pos] = key; cidx[pos] = (u32)i; }
        }
    }
}

// ---- Pass 4: exact rank by (key desc, idx asc); grid (CAP/256, CAP/1024) ----
__global__ void k_rank(const u32* __restrict__ ckey, const u32* __restrict__ cidx,
                       const u32* __restrict__ cnt, u32* __restrict__ rank) {
    int M = (int)min(cnt[0], (u32)CAP);
    int e = blockIdx.x * 256 + threadIdx.x;
    bool act = (e < M);
    u32 mykey = 0, myidx = 0;
    if (act) { mykey = ckey[e]; myidx = cidx[e]; }
    int j0 = blockIdx.y * 1024;
    int j1 = min(j0 + 1024, M);
    __shared__ u32 sk[256], si[256];
    u32 r = 0;
    for (int base = j0; base < j1; base += 256) {
        __syncthreads();
        int jj = base + threadIdx.x;
        if (jj < j1) { sk[threadIdx.x] = ckey[jj]; si[threadIdx.x] = cidx[jj]; }
        __syncthreads();
        int lim = min(256, j1 - base);
        if (act) {
            for (int q = 0; q < lim; ++q) {
                u32 kq = sk[q];
                r += (u32)((kq > mykey) || (kq == mykey && si[q] < myidx));
            }
        }
    }
    if (act && r) atomicAdd(&rank[e], r);
}

__global__ void k_scatter(const u32* __restrict__ ckey, const u32* __restrict__ cidx,
                          const u32* __restrict__ cnt, const u32* __restrict__ rank,
                          u32* __restrict__ skey, u32* __restrict__ sidx) {
    int M = (int)min(cnt[0], (u32)CAP);
    int e = blockIdx.x * 256 + threadIdx.x;
    if (e < M) {
        u32 r = rank[e];
        if (r < (u32)KCAND) { skey[r] = ckey[e]; sidx[r] = cidx[e]; }
    }
}

// ---- Pass 5: decode the 4096 selected boxes; build validity bitmask ----
__global__ void k_decode(const float* __restrict__ in, const u32* __restrict__ skey,
                         const u32* __restrict__ sidx, float* __restrict__ cand,
                         u64* __restrict__ keepg) {
#pragma clang fp contract(off)
    int r = blockIdx.x * 256 + threadIdx.x;   // grid 16 x 256 = 4096 exactly
    u32 key = skey[r];
    u32 idx = sidx[r];
    u32 a = idx % 3u;
    u32 rem = idx / 3u;
    u32 w = rem & 127u; rem >>= 7;
    u32 h = rem & 127u;
    u32 z = rem >> 7;
    float anch = (a == 0u) ? 10.0f : ((a == 1u) ? 30.0f : 60.0f);
    const float* p = in + (size_t)idx * 5;
    float s  = p[0];
    float zc = (1.5f + 4.0f * (float)z) + p[1] * anch;
    float yc = (1.5f + 4.0f * (float)h) + p[2] * anch;
    float xc = (1.5f + 4.0f * (float)w) + p[3] * anch;
    float d  = expf(p[4]) * anch;
    float* o = cand + (size_t)r * 5;
    o[0] = s; o[1] = zc; o[2] = yc; o[3] = xc; o[4] = d;
    u64 bal = __ballot(key != 0u);    // valid = score > THRESH (key==0 means filtered)
    if ((threadIdx.x & 63) == 0) keepg[r >> 6] = bal;
}

// ---- Pass 6: 4096x4096 suppression bitmask (bit set iff j>i && iou>=th) ----
__global__ void k_mask(const float* __restrict__ cand, u64* __restrict__ mask) {
#pragma clang fp contract(off)
    int i = blockIdx.y;
    int wv = blockIdx.x * 4 + (threadIdx.x >> 6);
    int j = wv * 64 + (threadIdx.x & 63);
    const float* bi = cand + (size_t)i * 5;
    const float* bj = cand + (size_t)j * 5;
    float zi = bi[1], yi = bi[2], xi = bi[3], di = bi[4];
    float zj = bj[1], yj = bj[2], xj = bj[3], dj = bj[4];
    float ri = di * 0.5f, rj = dj * 0.5f;
    float ov0 = fmaxf(0.0f, fminf(zi + ri, zj + rj) - fmaxf(zi - ri, zj - rj));
    float ov1 = fmaxf(0.0f, fminf(yi + ri, yj + rj) - fmaxf(yi - ri, yj - rj));
    float ov2 = fmaxf(0.0f, fminf(xi + ri, xj + rj) - fmaxf(xi - ri, xj - rj));
    float inter = (ov0 * ov1) * ov2;
    float vi = (di * di) * di;
    float vj = (dj * dj) * dj;
    float iou = inter / ((vi + vj) - inter);
    bool bit = (j > i) && (iou >= NMS_TH);
    u64 bal = __ballot(bit);
    if ((threadIdx.x & 63) == 0) mask[(size_t)i * 64 + wv] = bal;
}

// ---- Pass 7: greedy NMS — 8 waves stream tiles (MLP), wave 0 computes ----
// lane l of wave 0 holds keep word l. LDS double-buffers one 64x64-word
// chunk tile; each wave loads a 4 KB slice (8-way memory-level parallelism).
// One barrier per chunk. Resolve = scalar readlane greedy; apply = one-shot
// OR over kept rows (rows carry only j>i bits, so word c resolves exactly).
__global__ __launch_bounds__(512) void k_nms(const u64* __restrict__ mask,
                                             u64* __restrict__ keepg) {
    __shared__ u64 tile[2][4096];   // 2 x 32 KB, linear [row][word]
    int lane = threadIdx.x & 63;
    int wave = threadIdx.x >> 6;    // 0..7
    u64 K = (wave == 0) ? keepg[lane] : 0ull;

    // prologue: stage chunk 0 into tile[0] (each wave a 4 KB slice)
    {
        const char* src = (const char*)mask + wave * 4096 + lane * 16;
        char* dst = (char*)&tile[0][0] + wave * 4096;
#pragma unroll
        for (int i = 0; i < 4; ++i)
            GLD_LDS16(src + i * 1024, dst + i * 1024);
    }

    for (int c = 0; c < 64; ++c) {
        asm volatile("s_waitcnt vmcnt(0)" ::: "memory");   // own slice landed
        __syncthreads();                                    // all slices landed
        const u64* tl = &tile[c & 1][0];
        // issue next chunk's slice loads (flight hides under wave-0 compute)
        if (c + 1 < 64) {
            const char* src = (const char*)(mask + (size_t)(c + 1) * 4096) + wave * 4096 + lane * 16;
            char* dst = (char*)&tile[(c + 1) & 1][0] + wave * 4096;
#pragma unroll
            for (int i = 0; i < 4; ++i)
                GLD_LDS16(src + i * 1024, dst + i * 1024);
        }
        if (wave == 0) {
            // diag: lane b holds row b's word c (intra-chunk suppression bits)
            u64 diag = tl[lane * 64 + c];
            u32 dlo = (u32)diag, dhi = (u32)(diag >> 32);
            // kw = keep word c (wave-uniform)
            u32 kwlo = (u32)__builtin_amdgcn_readlane((int)(u32)K, c);
            u32 kwhi = (u32)__builtin_amdgcn_readlane((int)(u32)(K >> 32), c);
            u64 remaining = ((u64)kwhi << 32) | kwlo;
            // resolve: scalar greedy over surviving bits
            u64 kept = 0;
            while (remaining) {
                int b = __builtin_ctzll(remaining);
                kept |= 1ull << b;
                u32 rlo = (u32)__builtin_amdgcn_readlane((int)dlo, b);
                u32 rhi = (u32)__builtin_amdgcn_readlane((int)dhi, b);
                u64 rb = ((u64)rhi << 32) | rlo;   // bits > b only
                remaining &= ~(rb | (1ull << b));
            }
            // apply: sup_l = OR over kept b of tile[b][l]
            u64 s0 = 0, s1 = 0, s2 = 0, s3 = 0;
#pragma unroll
            for (int b = 0; b < 64; b += 4) {
                u64 m0 = ((kept >> (b + 0)) & 1ull) ? ~0ull : 0ull;
                u64 m1 = ((kept >> (b + 1)) & 1ull) ? ~0ull : 0ull;
                u64 m2 = ((kept >> (b + 2)) & 1ull) ? ~0ull : 0ull;
                u64 m3 = ((kept >> (b + 3)) & 1ull) ? ~0ull : 0ull;
                s0 |= tl[(b + 0) * 64 + lane] & m0;
                s1 |= tl[(b + 1) * 64 + lane] & m1;
                s2 |= tl[(b + 2) * 64 + lane] & m2;
                s3 |= tl[(b + 3) * 64 + lane] & m3;
            }
            K &= ~((s0 | s1) | (s2 | s3));
        }
    }
    if (wave == 0) keepg[lane] = K;
}

// ---- Pass 8: final top-300 = kept positions asc, then non-kept asc ----
__global__ void k_final(const float* __restrict__ cand, const u64* __restrict__ keepg,
                        float* __restrict__ outp) {
    __shared__ u64 kw[64];
    __shared__ u32 wp[65];
    int t = threadIdx.x;   // 256
    if (t < 64) kw[t] = keepg[t];
    __syncthreads();
    if (t == 0) {
        u32 acc = 0;
        for (int wv = 0; wv < 64; ++wv) { wp[wv] = acc; acc += (u32)__popcll(kw[wv]); }
        wp[64] = acc;
    }
    __syncthreads();
    u32 nk = wp[64];
    for (int r = t; r < KCAND; r += 256) {
        u64 word = kw[r >> 6];
        int b = r & 63;
        bool kept = (word >> b) & 1ull;
        u64 lowmask = b ? (~0ull >> (64 - b)) : 0ull;
        u32 before = wp[r >> 6] + (u32)__popcll(word & lowmask);
        u32 slot = kept ? before : (nk + (u32)r - before);
        if (slot < (u32)TOPK) {
            const float* src = cand + (size_t)r * 5;
            float* dst = outp + (size_t)slot * 5;
            dst[0] = src[0]; dst[1] = src[1]; dst[2] = src[2];
            dst[3] = src[3]; dst[4] = src[4];
        }
    }
}

extern "C" void kernel_launch(void* const* d_in, const int* in_sizes, int n_in,
                              void* d_out, int out_size, void* d_ws, size_t ws_size,
                              hipStream_t stream) {
    const float* in = (const float*)d_in[0];
    float* outp = (float*)d_out;
    char* ws = (char*)d_ws;

    // workspace layout (bytes), CAP = 16384
    u32* hist = (u32*)(ws + 0);            // 16384
    u32* cnt  = (u32*)(ws + 16384);        // 64
    u32* rank = (u32*)(ws + 16448);        // 65536
    u32* ckey = (u32*)(ws + 81984);        // 65536
    u32* cidx = (u32*)(ws + 147520);       // 65536
    u32* skey = (u32*)(ws + 213056);       // 16384
    u32* sidx = (u32*)(ws + 229440);       // 16384
    float* cand = (float*)(ws + 245824);   // 81920
    u64* keepg  = (u64*)(ws + 327744);     // 512
    u64* mask   = (u64*)(ws + 328256);     // 2097152   (total ~2.43 MB)

    hipMemsetAsync(hist, 0, 16384 + 64, stream);   // hist + cnt
    hipMemsetAsync(rank, 0, 65536, stream);

    k_hist   <<<2048, 256, 0, stream>>>(in, hist);
    k_pivot  <<<1, 256, 0, stream>>>(hist, cnt);
    k_compact<<<2048, 256, 0, stream>>>(in, cnt, ckey, cidx);
    k_rank   <<<dim3(64, 16), 256, 0, stream>>>(ckey, cidx, cnt, rank);
    k_scatter<<<64, 256, 0, stream>>>(ckey, cidx, cnt, rank, skey, sidx);
    k_decode <<<16, 256, 0, stream>>>(in, skey, sidx, cand, keepg);
    k_mask   <<<dim3(16, 4096), 256, 0, stream>>>(cand, mask);
    k_nms    <<<1, 512, 0, stream>>>(mask, keepg);
    k_final  <<<1, 256, 0, stream>>>(cand, keepg, outp);
}

// Round 7
// 246.179 us; speedup vs baseline: 4.5218x; 1.6431x over previous
//
#include <hip/hip_runtime.h>
#include <stdint.h>

typedef unsigned int u32;
typedef unsigned long long u64;

#define N_BOXES 6291456   // 128*128*128*3
#define KCAND 4096
#define TOPK 300
#define CAP 16384         // compact capacity; need >= 4095 + B* bin population (~8.5K for this data)
#define SCORE_TH -3.0f
#define NMS_TH 0.05f

#define GLD_LDS16(srcp, dstp) \
    __builtin_amdgcn_global_load_lds( \
        (const __attribute__((address_space(1))) u32*)(srcp), \
        (__attribute__((address_space(3))) u32*)(dstp), 16, 0, 0)

__device__ __forceinline__ u32 sortable(float f) {
    u32 b = __float_as_uint(f);
    return (b & 0x80000000u) ? ~b : (b | 0x80000000u);
}

// ---- Pass 1: 4096-bin histogram of top-12 bits of sortable key ----
__global__ void k_hist(const float* __restrict__ in, u32* __restrict__ hist) {
    __shared__ u32 lh[4096];
    for (int k = threadIdx.x; k < 4096; k += blockDim.x) lh[k] = 0;
    __syncthreads();
    int stride = gridDim.x * blockDim.x;
    for (int i = blockIdx.x * blockDim.x + threadIdx.x; i < N_BOXES; i += stride) {
        float f = in[(size_t)i * 5];
        u32 key = (f > SCORE_TH) ? sortable(f) : 0u;
        atomicAdd(&lh[key >> 20], 1u);
    }
    __syncthreads();
    for (int k = threadIdx.x; k < 4096; k += blockDim.x)
        if (lh[k]) atomicAdd(&hist[k], lh[k]);
}

// ---- Pass 2: find bin B* containing the 4096th largest key ----
__global__ void k_pivot(const u32* __restrict__ hist, u32* __restrict__ cnt) {
    __shared__ u32 part[256];
    int t = threadIdx.x;
    u32 s = 0;
    for (int k = 0; k < 16; ++k) s += hist[t * 16 + k];
    part[t] = s;
    __syncthreads();
    if (t == 0) {
        u32 acc = 0; int chunk = -1;
        for (int c = 255; c >= 0; --c) {
            if (acc + part[c] >= (u32)KCAND) { chunk = c; break; }
            acc += part[c];
        }
        u32 bstar = 0;
        if (chunk >= 0) {
            for (int b = chunk * 16 + 15; b >= chunk * 16; --b) {
                acc += hist[b];
                if (acc >= (u32)KCAND) { bstar = (u32)b; break; }
            }
        }
        cnt[1] = bstar;
    }
}

// ---- Pass 3: compact all candidates with bin >= B* ----
__global__ void k_compact(const float* __restrict__ in, u32* __restrict__ cnt,
                          u32* __restrict__ ckey, u32* __restrict__ cidx) {
    u32 bstar = cnt[1];
    int stride = gridDim.x * blockDim.x;
    for (int i = blockIdx.x * blockDim.x + threadIdx.x; i < N_BOXES; i += stride) {
        float f = in[(size_t)i * 5];
        u32 key = (f > SCORE_TH) ? sortable(f) : 0u;
        if ((key >> 20) >= bstar) {
            u32 pos = atomicAdd(&cnt[0], 1u);
            if (pos < (u32)CAP) { ckey[pos] = key; cidx[pos] = (u32)i; }
        }
    }
}

// ---- Pass 4: exact rank by (key desc, idx asc); grid (CAP/256, CAP/1024) ----
__global__ void k_rank(const u32* __restrict__ ckey, const u32* __restrict__ cidx,
                       const u32* __restrict__ cnt, u32* __restrict__ rank) {
    int M = (int)min(cnt[0], (u32)CAP);
    int e = blockIdx.x * 256 + threadIdx.x;
    bool act = (e < M);
    u32 mykey = 0, myidx = 0;
    if (act) { mykey = ckey[e]; myidx = cidx[e]; }
    int j0 = blockIdx.y * 1024;
    int j1 = min(j0 + 1024, M);
    __shared__ u32 sk[256], si[256];
    u32 r = 0;
    for (int base = j0; base < j1; base += 256) {
        __syncthreads();
        int jj = base + threadIdx.x;
        if (jj < j1) { sk[threadIdx.x] = ckey[jj]; si[threadIdx.x] = cidx[jj]; }
        __syncthreads();
        int lim = min(256, j1 - base);
        if (act) {
            for (int q = 0; q < lim; ++q) {
                u32 kq = sk[q];
                r += (u32)((kq > mykey) || (kq == mykey && si[q] < myidx));
            }
        }
    }
    if (act && r) atomicAdd(&rank[e], r);
}

__global__ void k_scatter(const u32* __restrict__ ckey, const u32* __restrict__ cidx,
                          const u32* __restrict__ cnt, const u32* __restrict__ rank,
                          u32* __restrict__ skey, u32* __restrict__ sidx) {
    int M = (int)min(cnt[0], (u32)CAP);
    int e = blockIdx.x * 256 + threadIdx.x;
    if (e < M) {
        u32 r = rank[e];
        if (r < (u32)KCAND) { skey[r] = ckey[e]; sidx[r] = cidx[e]; }
    }
}

// ---- Pass 5: decode the 4096 selected boxes; build validity bitmask ----
__global__ void k_decode(const float* __restrict__ in, const u32* __restrict__ skey,
                         const u32* __restrict__ sidx, float* __restrict__ cand,
                         u64* __restrict__ keepg) {
#pragma clang fp contract(off)
    int r = blockIdx.x * 256 + threadIdx.x;   // grid 16 x 256 = 4096 exactly
    u32 key = skey[r];
    u32 idx = sidx[r];
    u32 a = idx % 3u;
    u32 rem = idx / 3u;
    u32 w = rem & 127u; rem >>= 7;
    u32 h = rem & 127u;
    u32 z = rem >> 7;
    float anch = (a == 0u) ? 10.0f : ((a == 1u) ? 30.0f : 60.0f);
    const float* p = in + (size_t)idx * 5;
    float s  = p[0];
    float zc = (1.5f + 4.0f * (float)z) + p[1] * anch;
    float yc = (1.5f + 4.0f * (float)h) + p[2] * anch;
    float xc = (1.5f + 4.0f * (float)w) + p[3] * anch;
    float d  = expf(p[4]) * anch;
    float* o = cand + (size_t)r * 5;
    o[0] = s; o[1] = zc; o[2] = yc; o[3] = xc; o[4] = d;
    u64 bal = __ballot(key != 0u);    // valid = score > THRESH (key==0 means filtered)
    if ((threadIdx.x & 63) == 0) keepg[r >> 6] = bal;
}

// ---- Pass 6: 4096x4096 suppression bitmask (bit set iff j>i && iou>=th) ----
__global__ void k_mask(const float* __restrict__ cand, u64* __restrict__ mask) {
#pragma clang fp contract(off)
    int i = blockIdx.y;
    int wv = blockIdx.x * 4 + (threadIdx.x >> 6);
    int j = wv * 64 + (threadIdx.x & 63);
    const float* bi = cand + (size_t)i * 5;
    const float* bj = cand + (size_t)j * 5;
    float zi = bi[1], yi = bi[2], xi = bi[3], di = bi[4];
    float zj = bj[1], yj = bj[2], xj = bj[3], dj = bj[4];
    float ri = di * 0.5f, rj = dj * 0.5f;
    float ov0 = fmaxf(0.0f, fminf(zi + ri, zj + rj) - fmaxf(zi - ri, zj - rj));
    float ov1 = fmaxf(0.0f, fminf(yi + ri, yj + rj) - fmaxf(yi - ri, yj - rj));
    float ov2 = fmaxf(0.0f, fminf(xi + ri, xj + rj) - fmaxf(xi - ri, xj - rj));
    float inter = (ov0 * ov1) * ov2;
    float vi = (di * di) * di;
    float vj = (dj * dj) * dj;
    float iou = inter / ((vi + vj) - inter);
    bool bit = (j > i) && (iou >= NMS_TH);
    u64 bal = __ballot(bit);
    if ((threadIdx.x & 63) == 0) mask[(size_t)i * 64 + wv] = bal;
}

// ---- Pass 7: greedy NMS — 8-wave tile streaming + EARLY EXIT at 300 kept ----
// lane l of wave 0 holds keep word l. Once >=TOPK boxes are kept, all later
// keep decisions are irrelevant to the output (fillers map to slots >= 300),
// so we stop. cnt[3] records the last RESOLVED word; k_final ignores words
// beyond it. If fewer than TOPK are kept in total, we run all 64 chunks and
// the path is identical to the proven full version.
__global__ __launch_bounds__(512) void k_nms(const u64* __restrict__ mask,
                                             u64* __restrict__ keepg,
                                             u32* __restrict__ cnt) {
    __shared__ u64 tile[2][4096];   // 2 x 32 KB, linear [row][word]
    __shared__ int sstop;
    int lane = threadIdx.x & 63;
    int wave = threadIdx.x >> 6;    // 0..7
    u64 K = (wave == 0) ? keepg[lane] : 0ull;
    int keptTotal = 0;
    if (threadIdx.x == 0) sstop = 64;

    // prologue: stage chunk 0 into tile[0] (each wave a 4 KB slice)
    {
        const char* src = (const char*)mask + wave * 4096 + lane * 16;
        char* dst = (char*)&tile[0][0] + wave * 4096;
#pragma unroll
        for (int i = 0; i < 4; ++i)
            GLD_LDS16(src + i * 1024, dst + i * 1024);
    }

    int resolved = 63;
    for (int c = 0; c < 64; ++c) {
        asm volatile("s_waitcnt vmcnt(0)" ::: "memory");   // own slice landed
        __syncthreads();                                    // all slices landed; orders sstop
        if (c > sstop) { resolved = sstop; break; }
        const u64* tl = &tile[c & 1][0];
        // issue next chunk's slice loads (flight hides under wave-0 compute)
        if (c + 1 < 64) {
            const char* src = (const char*)(mask + (size_t)(c + 1) * 4096) + wave * 4096 + lane * 16;
            char* dst = (char*)&tile[(c + 1) & 1][0] + wave * 4096;
#pragma unroll
            for (int i = 0; i < 4; ++i)
                GLD_LDS16(src + i * 1024, dst + i * 1024);
        }
        if (wave == 0) {
            // diag: lane b holds row b's word c (intra-chunk suppression bits)
            u64 diag = tl[lane * 64 + c];
            u32 dlo = (u32)diag, dhi = (u32)(diag >> 32);
            // kw = keep word c (wave-uniform)
            u32 kwlo = (u32)__builtin_amdgcn_readlane((int)(u32)K, c);
            u32 kwhi = (u32)__builtin_amdgcn_readlane((int)(u32)(K >> 32), c);
            u64 remaining = ((u64)kwhi << 32) | kwlo;
            // resolve: scalar greedy over surviving bits
            u64 kept = 0;
            while (remaining) {
                int b = __builtin_ctzll(remaining);
                kept |= 1ull << b;
                u32 rlo = (u32)__builtin_amdgcn_readlane((int)dlo, b);
                u32 rhi = (u32)__builtin_amdgcn_readlane((int)dhi, b);
                u64 rb = ((u64)rhi << 32) | rlo;   // bits > b only
                remaining &= ~(rb | (1ull << b));
            }
            // apply: sup_l = OR over kept b of tile[b][l]
            u64 s0 = 0, s1 = 0, s2 = 0, s3 = 0;
#pragma unroll
            for (int b = 0; b < 64; b += 4) {
                u64 m0 = ((kept >> (b + 0)) & 1ull) ? ~0ull : 0ull;
                u64 m1 = ((kept >> (b + 1)) & 1ull) ? ~0ull : 0ull;
                u64 m2 = ((kept >> (b + 2)) & 1ull) ? ~0ull : 0ull;
                u64 m3 = ((kept >> (b + 3)) & 1ull) ? ~0ull : 0ull;
                s0 |= tl[(b + 0) * 64 + lane] & m0;
                s1 |= tl[(b + 1) * 64 + lane] & m1;
                s2 |= tl[(b + 2) * 64 + lane] & m2;
                s3 |= tl[(b + 3) * 64 + lane] & m3;
            }
            K &= ~((s0 | s1) | (s2 | s3));
            keptTotal += (int)__popcll(kept);
            // word c is final; if we have TOPK kept, later words don't matter
            if (lane == 0 && keptTotal >= TOPK && sstop == 64) sstop = c;
        }
    }
    // drain any in-flight LDS-DMA before workgroup teardown
    asm volatile("s_waitcnt vmcnt(0)" ::: "memory");
    __syncthreads();
    if (wave == 0) {
        keepg[lane] = K;
        if (lane == 0) cnt[3] = (u32)resolved;   // last word with final keep bits
    }
}

// ---- Pass 8: final top-300 = kept positions asc, then non-kept asc ----
// Only words 0..cnt[3] are final; rows beyond can only map to slots >= TOPK
// (they exist only when >= TOPK boxes were already kept), so skipping them
// is exact.
__global__ void k_final(const float* __restrict__ cand, const u64* __restrict__ keepg,
                        const u32* __restrict__ cnt, float* __restrict__ outp) {
    __shared__ u64 kw[64];
    __shared__ u32 wp[65];
    int t = threadIdx.x;   // 256
    int limit = (int)cnt[3];
    if (t < 64) kw[t] = (t <= limit) ? keepg[t] : 0ull;
    __syncthreads();
    if (t == 0) {
        u32 acc = 0;
        for (int wv = 0; wv < 64; ++wv) { wp[wv] = acc; acc += (u32)__popcll(kw[wv]); }
        wp[64] = acc;
    }
    __syncthreads();
    u32 nk = wp[64];
    int rmax = (limit + 1) * 64;
    for (int r = t; r < rmax; r += 256) {
        u64 word = kw[r >> 6];
        int b = r & 63;
        bool kept = (word >> b) & 1ull;
        u64 lowmask = b ? (~0ull >> (64 - b)) : 0ull;
        u32 before = wp[r >> 6] + (u32)__popcll(word & lowmask);
        u32 slot = kept ? before : (nk + (u32)r - before);
        if (slot < (u32)TOPK) {
            const float* src = cand + (size_t)r * 5;
            float* dst = outp + (size_t)slot * 5;
            dst[0] = src[0]; dst[1] = src[1]; dst[2] = src[2];
            dst[3] = src[3]; dst[4] = src[4];
        }
    }
}

extern "C" void kernel_launch(void* const* d_in, const int* in_sizes, int n_in,
                              void* d_out, int out_size, void* d_ws, size_t ws_size,
                              hipStream_t stream) {
    const float* in = (const float*)d_in[0];
    float* outp = (float*)d_out;
    char* ws = (char*)d_ws;

    // workspace layout (bytes), CAP = 16384
    u32* hist = (u32*)(ws + 0);            // 16384
    u32* cnt  = (u32*)(ws + 16384);        // 64
    u32* rank = (u32*)(ws + 16448);        // 65536
    u32* ckey = (u32*)(ws + 81984);        // 65536
    u32* cidx = (u32*)(ws + 147520);       // 65536
    u32* skey = (u32*)(ws + 213056);       // 16384
    u32* sidx = (u32*)(ws + 229440);       // 16384
    float* cand = (float*)(ws + 245824);   // 81920
    u64* keepg  = (u64*)(ws + 327744);     // 512
    u64* mask   = (u64*)(ws + 328256);     // 2097152   (total ~2.43 MB)

    hipMemsetAsync(ws, 0, 81984, stream);   // hist + cnt + rank (contiguous)

    k_hist   <<<2048, 256, 0, stream>>>(in, hist);
    k_pivot  <<<1, 256, 0, stream>>>(hist, cnt);
    k_compact<<<2048, 256, 0, stream>>>(in, cnt, ckey, cidx);
    k_rank   <<<dim3(64, 16), 256, 0, stream>>>(ckey, cidx, cnt, rank);
    k_scatter<<<64, 256, 0, stream>>>(ckey, cidx, cnt, rank, skey, sidx);
    k_decode <<<16, 256, 0, stream>>>(in, skey, sidx, cand, keepg);
    k_mask   <<<dim3(16, 4096), 256, 0, stream>>>(cand, mask);
    k_nms    <<<1, 512, 0, stream>>>(mask, keepg, cnt);
    k_final  <<<1, 256, 0, stream>>>(cand, keepg, cnt, outp);
}